// Round 3
// baseline (112.604 us; speedup 1.0000x reference)
//
#include <hip/hip_runtime.h>

#define NBINS 10
#define C 10

constexpr int BLOCK = 256;
constexpr int GRID  = 2048;
constexpr int PAIRS_PER_TILE = BLOCK;               // 256 pairs = 512 samples / tile
constexpr int F4_PER_TILE    = PAIRS_PER_TILE * 5;  // 1280 float4 = 5120 floats

__global__ __launch_bounds__(BLOCK) void ece_main(
    const float4* __restrict__ p4,
    const int2*   __restrict__ l2,
    double*       __restrict__ g_conf,   // S_t totals (cumulative conf sums)
    unsigned int* __restrict__ g_cnt,    // G_t totals (cumulative counts)
    unsigned int* __restrict__ g_cor,    // per-bin correct counts
    int npairs, int nf4)
{
    __shared__ float        s_stage[F4_PER_TILE * 4];   // 20 KB staging tile
    __shared__ unsigned int s_cor[NBINS];
    __shared__ float        s_conf_red[4 * NBINS];
    __shared__ unsigned int s_cnt_red [4 * NBINS];

    const int tid = threadIdx.x;
    if (tid < NBINS) s_cor[tid] = 0u;

    // exact float32 of np.arange(0,1.1,0.1) edges (double mult, then narrow)
    const float EDGE[NBINS] = {
        (float)(0*0.1), (float)(1*0.1), (float)(2*0.1), (float)(3*0.1), (float)(4*0.1),
        (float)(5*0.1), (float)(6*0.1), (float)(7*0.1), (float)(8*0.1), (float)(9*0.1)};

    unsigned int cnt[NBINS];
    float        conf[NBINS];
#pragma unroll
    for (int t = 0; t < NBINS; ++t) { cnt[t] = 0u; conf[t] = 0.0f; }

    float4* s4 = reinterpret_cast<float4*>(s_stage);
    const int ntiles = (npairs + PAIRS_PER_TILE - 1) / PAIRS_PER_TILE;

    for (int tile = blockIdx.x; tile < ntiles; tile += GRID) {
        __syncthreads();   // protect s_stage reuse (and s_cor init on first pass)

        const int f4base = tile * F4_PER_TILE;
        // ---- element phase: coalesced loads, register cumulative histogram ----
#pragma unroll
        for (int k = 0; k < 5; ++k) {
            const int fi = f4base + k * BLOCK + tid;
            float4 q = make_float4(0.0f, 0.0f, 0.0f, 0.0f);
            if (fi < nf4) q = p4[fi];
            s4[k * BLOCK + tid] = q;                    // linear LDS write (conflict-free)
            const float e[4] = {q.x, q.y, q.z, q.w};
#pragma unroll
            for (int j = 0; j < 4; ++j) {
                const float x = e[j];
#pragma unroll
                for (int t = 0; t < NBINS; ++t) {
                    const bool g = x > EDGE[t];
                    cnt[t]  += g ? 1u : 0u;
                    conf[t] += g ? x : 0.0f;
                }
            }
        }
        __syncthreads();

        // ---- sample phase: each thread reads its pair (80 B) from LDS ----
        const int pr = tile * PAIRS_PER_TILE + tid;
        if (pr < npairs) {
            const float4* row = reinterpret_cast<const float4*>(&s_stage[tid * 20]);
            const float4 q0 = row[0], q1 = row[1], q2 = row[2], q3 = row[3], q4 = row[4];
            const int2 lab = l2[pr];

            const float a[C] = {q0.x,q0.y,q0.z,q0.w, q1.x,q1.y,q1.z,q1.w, q2.x,q2.y};
            const float b[C] = {q2.z,q2.w, q3.x,q3.y,q3.z,q3.w, q4.x,q4.y,q4.z,q4.w};

#pragma unroll
            for (int s = 0; s < 2; ++s) {
                const float* p = (s == 0) ? a : b;      // fully unrolled -> static
                const int  lbl = (s == 0) ? lab.x : lab.y;

                float mx = p[0]; int arg = 0;           // first-occurrence argmax
#pragma unroll
                for (int j = 1; j < C; ++j) {
                    if (p[j] > mx) { mx = p[j]; arg = j; }
                }
                if (arg == lbl) {
                    int im = -1;
#pragma unroll
                    for (int t = 0; t < NBINS; ++t) im += (mx > EDGE[t]) ? 1 : 0;
                    if (im >= 0) atomicAdd(&s_cor[im], 1u);
                }
            }
        }
    }
    __syncthreads();

    // ---- 64-lane butterfly reduce each accumulator ----
#pragma unroll
    for (int t = 0; t < NBINS; ++t) {
        for (int o = 32; o > 0; o >>= 1) {
            cnt[t]  += __shfl_xor(cnt[t],  o, 64);
            conf[t] += __shfl_xor(conf[t], o, 64);
        }
    }

    const int wave = tid >> 6, lane = tid & 63;
    if (lane == 0) {
#pragma unroll
        for (int t = 0; t < NBINS; ++t) {
            s_cnt_red [wave * NBINS + t] = cnt[t];
            s_conf_red[wave * NBINS + t] = conf[t];
        }
    }
    __syncthreads();

    if (tid < NBINS) {
        unsigned int c = 0; float f = 0.0f;
#pragma unroll
        for (int w = 0; w < 4; ++w) {
            c += s_cnt_red [w * NBINS + tid];
            f += s_conf_red[w * NBINS + tid];
        }
        atomicAdd(&g_cnt [tid], c);
        atomicAdd(&g_conf[tid], (double)f);
        atomicAdd(&g_cor [tid], s_cor[tid]);
    }
}

__global__ void ece_final(const double* __restrict__ g_conf,
                          const unsigned int* __restrict__ g_cnt,
                          const unsigned int* __restrict__ g_cor,
                          float* __restrict__ out)
{
    if (threadIdx.x == 0 && blockIdx.x == 0) {
        const float edges[11] = {0.0f,0.1f,0.2f,0.3f,0.4f,0.5f,
                                 0.6f,0.7f,0.8f,0.9f,1.0f};
        double total = 0.0, ece = 0.0;
        for (int j = 0; j < NBINS; ++j) {
            const double c  = (double)g_cnt[j] - (j < 9 ? (double)g_cnt[j+1] : 0.0);
            const double sc = g_conf[j]        - (j < 9 ? g_conf[j+1]        : 0.0);
            const double ba = (double)g_cor[j] / c;
            total += c;
            ece   += fabs(sc / c - ba) * c;
            out[1 + j]  = edges[j + 1] - 0.05f;   // bin centers
            out[11 + j] = (float)ba;              // bin accuracy
        }
        out[0] = (float)(ece / total);
    }
}

extern "C" void kernel_launch(void* const* d_in, const int* in_sizes, int n_in,
                              void* d_out, int out_size, void* d_ws, size_t ws_size,
                              hipStream_t stream)
{
    const float* probs  = (const float*)d_in[0];
    const int*   labels = (const int*)  d_in[1];
    float*       out    = (float*)d_out;
    const int n      = in_sizes[1];       // N_SAMPLES (even)
    const int npairs = n / 2;
    const int nf4    = (n * C) / 4;       // 5,000,000 float4s

    // ws layout: [0,80) double S_t[10] | [80,120) uint G_t[10] | [120,160) uint cor[10]
    double*       g_conf = (double*)d_ws;
    unsigned int* g_cnt  = (unsigned int*)((char*)d_ws + 80);
    unsigned int* g_cor  = (unsigned int*)((char*)d_ws + 120);

    hipMemsetAsync(d_ws, 0, 160, stream);   // ws is not re-poisoned between replays
    ece_main<<<GRID, BLOCK, 0, stream>>>((const float4*)probs, (const int2*)labels,
                                         g_conf, g_cnt, g_cor, npairs, nf4);
    ece_final<<<1, 64, 0, stream>>>(g_conf, g_cnt, g_cor, out);
}

// Round 4
// 79.062 us; speedup vs baseline: 1.4242x; 1.4242x over previous
//
#include <hip/hip_runtime.h>

#define NBINS 10
#define C 10

constexpr int BLOCK = 256;
constexpr int GRID1 = 1024;
constexpr int PAIRS_PER_TILE = BLOCK;               // 256 pairs = 512 samples / tile
constexpr int F4_PER_TILE    = PAIRS_PER_TILE * 5;  // 1280 float4 = 5120 floats
constexpr int PSTR = 32;                            // padded partial-row stride (floats)

// ws layout: [0] conf partials GRID1*32 f32 | [1] cnt partials | [2] cor partials
// total = 3 * 1024 * 32 * 4 B = 393 KB. Plain stores only — NO global atomics.

__global__ __launch_bounds__(BLOCK) void ece_main(
    const float4* __restrict__ p4,
    const int2*   __restrict__ l2,
    float*        __restrict__ part,
    int npairs, int nf4)
{
    __shared__ float        s_stage[F4_PER_TILE * 4];   // 20 KB staging tile
    __shared__ unsigned int s_cor[NBINS];
    __shared__ float        s_conf_red[4 * NBINS];
    __shared__ unsigned int s_cnt_red [4 * NBINS];

    const int tid = threadIdx.x;
    if (tid < NBINS) s_cor[tid] = 0u;

    // exact float32 of np.arange(0,1.1,0.1) edges (f64 mult, then narrow)
    const float EDGE[NBINS] = {
        (float)(0*0.1), (float)(1*0.1), (float)(2*0.1), (float)(3*0.1), (float)(4*0.1),
        (float)(5*0.1), (float)(6*0.1), (float)(7*0.1), (float)(8*0.1), (float)(9*0.1)};

    unsigned int cnt[NBINS];
    float        conf[NBINS];
#pragma unroll
    for (int t = 0; t < NBINS; ++t) { cnt[t] = 0u; conf[t] = 0.0f; }

    float4* s4 = reinterpret_cast<float4*>(s_stage);
    const int ntiles = (npairs + PAIRS_PER_TILE - 1) / PAIRS_PER_TILE;

    for (int tile = blockIdx.x; tile < ntiles; tile += GRID1) {
        __syncthreads();   // protect s_stage reuse (and s_cor init on first pass)

        const int f4base = tile * F4_PER_TILE;
        // ---- element phase: coalesced loads, register cumulative histogram ----
#pragma unroll
        for (int k = 0; k < 5; ++k) {
            const int fi = f4base + k * BLOCK + tid;
            float4 q = make_float4(0.0f, 0.0f, 0.0f, 0.0f);
            if (fi < nf4) q = p4[fi];
            s4[k * BLOCK + tid] = q;                    // linear LDS write
            const float e[4] = {q.x, q.y, q.z, q.w};
#pragma unroll
            for (int j = 0; j < 4; ++j) {
                const float x = e[j];
#pragma unroll
                for (int t = 0; t < NBINS; ++t) {
                    const bool g = x > EDGE[t];
                    cnt[t]  += g ? 1u : 0u;
                    conf[t] += g ? x : 0.0f;
                }
            }
        }
        __syncthreads();

        // ---- sample phase: each thread reads its pair (80 B) from LDS ----
        const int pr = tile * PAIRS_PER_TILE + tid;
        if (pr < npairs) {
            const float4* row = reinterpret_cast<const float4*>(&s_stage[tid * 20]);
            const float4 q0 = row[0], q1 = row[1], q2 = row[2], q3 = row[3], q4 = row[4];
            const int2 lab = l2[pr];

            const float a[C] = {q0.x,q0.y,q0.z,q0.w, q1.x,q1.y,q1.z,q1.w, q2.x,q2.y};
            const float b[C] = {q2.z,q2.w, q3.x,q3.y,q3.z,q3.w, q4.x,q4.y,q4.z,q4.w};

#pragma unroll
            for (int s = 0; s < 2; ++s) {
                const float* p = (s == 0) ? a : b;      // fully unrolled -> static
                const int  lbl = (s == 0) ? lab.x : lab.y;

                float mx = p[0]; int arg = 0;           // first-occurrence argmax
#pragma unroll
                for (int j = 1; j < C; ++j) {
                    if (p[j] > mx) { mx = p[j]; arg = j; }
                }
                if (arg == lbl) {
                    int im = -1;
#pragma unroll
                    for (int t = 0; t < NBINS; ++t) im += (mx > EDGE[t]) ? 1 : 0;
                    if (im >= 0) atomicAdd(&s_cor[im], 1u);   // LDS only, rare
                }
            }
        }
    }
    __syncthreads();

    // ---- 64-lane butterfly reduce each accumulator ----
#pragma unroll
    for (int t = 0; t < NBINS; ++t) {
        for (int o = 32; o > 0; o >>= 1) {
            cnt[t]  += __shfl_xor(cnt[t],  o, 64);
            conf[t] += __shfl_xor(conf[t], o, 64);
        }
    }

    const int wave = tid >> 6, lane = tid & 63;
    if (lane == 0) {
#pragma unroll
        for (int t = 0; t < NBINS; ++t) {
            s_cnt_red [wave * NBINS + t] = cnt[t];
            s_conf_red[wave * NBINS + t] = conf[t];
        }
    }
    __syncthreads();

    // ---- per-block partials: plain stores, zero contention ----
    if (tid < NBINS) {
        unsigned int c = 0; float f = 0.0f;
#pragma unroll
        for (int w = 0; w < 4; ++w) {
            c += s_cnt_red [w * NBINS + tid];
            f += s_conf_red[w * NBINS + tid];
        }
        const int row = blockIdx.x * PSTR + tid;
        part[row]                   = f;                  // conf partial (f32 exact enough)
        part[GRID1 * PSTR + row]    = (float)c;           // cnt partial (<2^24, exact)
        part[2 * GRID1 * PSTR + row] = (float)s_cor[tid]; // cor partial (exact)
    }
}

__global__ __launch_bounds__(256) void ece_reduce(
    const float* __restrict__ part,
    float* __restrict__ out)
{
    __shared__ double       s_conf[4][NBINS];
    __shared__ unsigned int s_cnt [4][NBINS];
    __shared__ unsigned int s_cor [4][NBINS];

    const int tid = threadIdx.x;

    double       conf[NBINS];
    unsigned int cnt[NBINS], cor[NBINS];
#pragma unroll
    for (int t = 0; t < NBINS; ++t) { conf[t] = 0.0; cnt[t] = 0u; cor[t] = 0u; }

    for (int b = tid; b < GRID1; b += 256) {
        const float4* rc = reinterpret_cast<const float4*>(part + b * PSTR);
        const float4* rn = reinterpret_cast<const float4*>(part + GRID1 * PSTR + b * PSTR);
        const float4* rr = reinterpret_cast<const float4*>(part + 2 * GRID1 * PSTR + b * PSTR);
        const float4 c0 = rc[0], c1 = rc[1], c2 = rc[2];
        const float4 n0 = rn[0], n1 = rn[1], n2 = rn[2];
        const float4 r0 = rr[0], r1 = rr[1], r2 = rr[2];
        const float cf[NBINS] = {c0.x,c0.y,c0.z,c0.w, c1.x,c1.y,c1.z,c1.w, c2.x,c2.y};
        const float nf[NBINS] = {n0.x,n0.y,n0.z,n0.w, n1.x,n1.y,n1.z,n1.w, n2.x,n2.y};
        const float rf[NBINS] = {r0.x,r0.y,r0.z,r0.w, r1.x,r1.y,r1.z,r1.w, r2.x,r2.y};
#pragma unroll
        for (int t = 0; t < NBINS; ++t) {
            conf[t] += (double)cf[t];
            cnt[t]  += (unsigned int)nf[t];
            cor[t]  += (unsigned int)rf[t];
        }
    }

#pragma unroll
    for (int t = 0; t < NBINS; ++t) {
        for (int o = 32; o > 0; o >>= 1) {
            conf[t] += __shfl_xor(conf[t], o, 64);
            cnt[t]  += __shfl_xor(cnt[t],  o, 64);
            cor[t]  += __shfl_xor(cor[t],  o, 64);
        }
    }

    const int wave = tid >> 6, lane = tid & 63;
    if (lane == 0) {
#pragma unroll
        for (int t = 0; t < NBINS; ++t) {
            s_conf[wave][t] = conf[t];
            s_cnt [wave][t] = cnt[t];
            s_cor [wave][t] = cor[t];
        }
    }
    __syncthreads();

    if (tid == 0) {
        const float edges[11] = {
            (float)(0*0.1), (float)(1*0.1), (float)(2*0.1), (float)(3*0.1),
            (float)(4*0.1), (float)(5*0.1), (float)(6*0.1), (float)(7*0.1),
            (float)(8*0.1), (float)(9*0.1), (float)(10*0.1)};
        double tc[NBINS], tn[NBINS], tr[NBINS];
#pragma unroll
        for (int t = 0; t < NBINS; ++t) {
            tc[t] = s_conf[0][t] + s_conf[1][t] + s_conf[2][t] + s_conf[3][t];
            tn[t] = (double)(s_cnt[0][t] + s_cnt[1][t] + s_cnt[2][t] + s_cnt[3][t]);
            tr[t] = (double)(s_cor[0][t] + s_cor[1][t] + s_cor[2][t] + s_cor[3][t]);
        }
        double total = 0.0, ece = 0.0;
        for (int j = 0; j < NBINS; ++j) {
            const double c  = tn[j] - (j < 9 ? tn[j+1] : 0.0);   // cumulative -> per-bin
            const double sc = tc[j] - (j < 9 ? tc[j+1] : 0.0);
            const double ba = tr[j] / c;
            total += c;
            ece   += fabs(sc / c - ba) * c;
            out[1 + j]  = edges[j + 1] - 0.05f;   // bin centers
            out[11 + j] = (float)ba;              // bin accuracy
        }
        out[0] = (float)(ece / total);
    }
}

extern "C" void kernel_launch(void* const* d_in, const int* in_sizes, int n_in,
                              void* d_out, int out_size, void* d_ws, size_t ws_size,
                              hipStream_t stream)
{
    const float* probs  = (const float*)d_in[0];
    const int*   labels = (const int*)  d_in[1];
    float*       out    = (float*)d_out;
    const int n      = in_sizes[1];       // N_SAMPLES (even)
    const int npairs = n / 2;
    const int nf4    = (n * C) / 4;

    float* part = (float*)d_ws;           // 393 KB of scratch, fully overwritten each call

    ece_main<<<GRID1, BLOCK, 0, stream>>>((const float4*)probs, (const int2*)labels,
                                          part, npairs, nf4);
    ece_reduce<<<1, 256, 0, stream>>>(part, out);
}

// Round 5
// 57.504 us; speedup vs baseline: 1.9582x; 1.3749x over previous
//
#include <hip/hip_runtime.h>

#define NBINS 10
#define C 10

constexpr int BLOCK = 256;
constexpr int GRIDH = 1024;   // hist blocks == partial rows
constexpr int GRIDA = 1024;   // argmax blocks == partial rows
constexpr int PSTR  = 32;     // padded partial-row stride (floats)

// d_ws float layout:
//   [0, GRIDH*PSTR)                  conf' partials  (relu sums, cumulative per edge)
//   [GRIDH*PSTR, 2*GRIDH*PSTR)       cnt partials    (G_t counts, f32-exact <2^24)
//   [2*GRIDH*PSTR, +GRIDA*PSTR)      cor partials
// Every slot read by ece_reduce is rewritten by ece_hist/ece_arg each call.

__global__ __launch_bounds__(BLOCK) void ece_hist(
    const float4* __restrict__ p4,
    float*        __restrict__ part,
    int nf4)
{
    __shared__ float s_conf[4][NBINS];
    __shared__ float s_cnt [4][NBINS];

    const int tid  = threadIdx.x;
    const int lane = tid & 63, wave = tid >> 6;

    const float EDGE[NBINS] = {
        (float)(0*0.1), (float)(1*0.1), (float)(2*0.1), (float)(3*0.1), (float)(4*0.1),
        (float)(5*0.1), (float)(6*0.1), (float)(7*0.1), (float)(8*0.1), (float)(9*0.1)};

    float        conf[NBINS];   // per-lane relu partial sums
    unsigned int cnt[NBINS];    // wave-uniform ballot counts (lane 0 authoritative)
#pragma unroll
    for (int t = 0; t < NBINS; ++t) { conf[t] = 0.0f; cnt[t] = 0u; }

    const int gstride = GRIDH * BLOCK;
    for (int fi = blockIdx.x * BLOCK + tid; fi < nf4; fi += gstride) {
        const float4 q = p4[fi];                 // fully coalesced stream
        const float e[4] = {q.x, q.y, q.z, q.w};
#pragma unroll
        for (int j = 0; j < 4; ++j) {
            const float x = e[j];
#pragma unroll
            for (int t = 0; t < NBINS; ++t) {
                // counts: one v_cmp per 64 elements; popc+add ride the scalar pipe
                cnt[t] += (unsigned)__popcll(__ballot(x > EDGE[t]));
                // conf: sum of max(x-E,0); E*G_t correction added in reduce
                conf[t] += fmaxf(x - EDGE[t], 0.0f);
            }
        }
    }

    // conf: 64-lane butterfly; cnt: wave-uniform already (take lane 0)
#pragma unroll
    for (int t = 0; t < NBINS; ++t)
        for (int o = 32; o > 0; o >>= 1)
            conf[t] += __shfl_xor(conf[t], o, 64);

    if (lane == 0) {
#pragma unroll
        for (int t = 0; t < NBINS; ++t) {
            s_conf[wave][t] = conf[t];
            s_cnt [wave][t] = (float)cnt[t];
        }
    }
    __syncthreads();

    if (tid < 12) {   // write 12 slots (2 zero pads) so reduce can float4-load
        float fc = 0.0f, fn = 0.0f;
        if (tid < NBINS) {
#pragma unroll
            for (int w = 0; w < 4; ++w) { fc += s_conf[w][tid]; fn += s_cnt[w][tid]; }
        }
        part[(size_t)blockIdx.x * PSTR + tid]               = fc;
        part[(size_t)GRIDH * PSTR + blockIdx.x * PSTR + tid] = fn;
    }
}

__global__ __launch_bounds__(BLOCK) void ece_arg(
    const float4* __restrict__ p4,
    const int2*   __restrict__ l2,
    float*        __restrict__ part,
    int npairs)
{
    __shared__ unsigned int s_cor[NBINS];
    const int tid = threadIdx.x;
    if (tid < NBINS) s_cor[tid] = 0u;
    __syncthreads();

    const int gstride = GRIDA * BLOCK;
    for (int pr = blockIdx.x * BLOCK + tid; pr < npairs; pr += gstride) {
        const float4* row = p4 + (size_t)pr * 5;   // 80 B per pair, L3-resident
        const float4 q0 = row[0], q1 = row[1], q2 = row[2], q3 = row[3], q4 = row[4];
        const int2 lab = l2[pr];

        const float a[C] = {q0.x,q0.y,q0.z,q0.w, q1.x,q1.y,q1.z,q1.w, q2.x,q2.y};
        const float b[C] = {q2.z,q2.w, q3.x,q3.y,q3.z,q3.w, q4.x,q4.y,q4.z,q4.w};

#pragma unroll
        for (int s = 0; s < 2; ++s) {
            const float* p = (s == 0) ? a : b;     // fully unrolled -> static
            const int  lbl = (s == 0) ? lab.x : lab.y;

            float mx = p[0]; int arg = 0;          // first-occurrence argmax
#pragma unroll
            for (int j = 1; j < C; ++j)
                if (p[j] > mx) { mx = p[j]; arg = j; }

            if (arg == lbl) {
                // ceilf bin (validated bit-exact vs digitize in round 1)
                const int im = min((int)ceilf(mx * 10.0f) - 1, NBINS - 1);
                if (im >= 0) atomicAdd(&s_cor[im], 1u);
            }
        }
    }
    __syncthreads();

    if (tid < 12) {
        const float v = (tid < NBINS) ? (float)s_cor[tid] : 0.0f;
        part[(size_t)2 * GRIDH * PSTR + blockIdx.x * PSTR + tid] = v;
    }
}

__global__ __launch_bounds__(256) void ece_reduce(
    const float* __restrict__ part,
    float* __restrict__ out)
{
    __shared__ double s_c[4][NBINS];
    __shared__ double s_n[4][NBINS];
    __shared__ double s_r[4][NBINS];

    const int tid = threadIdx.x;
    const int lane = tid & 63, wave = tid >> 6;

    double conf[NBINS], cntd[NBINS], cord[NBINS];
#pragma unroll
    for (int t = 0; t < NBINS; ++t) { conf[t] = 0.0; cntd[t] = 0.0; cord[t] = 0.0; }

    for (int b = tid; b < GRIDH; b += 256) {
        const float4* rc = reinterpret_cast<const float4*>(part + (size_t)b * PSTR);
        const float4* rn = reinterpret_cast<const float4*>(part + (size_t)GRIDH * PSTR + b * PSTR);
        const float4* rr = reinterpret_cast<const float4*>(part + (size_t)2 * GRIDH * PSTR + b * PSTR);
        const float4 c0 = rc[0], c1 = rc[1], c2 = rc[2];
        const float4 n0 = rn[0], n1 = rn[1], n2 = rn[2];
        const float4 r0 = rr[0], r1 = rr[1], r2 = rr[2];
        const float cf[12] = {c0.x,c0.y,c0.z,c0.w, c1.x,c1.y,c1.z,c1.w, c2.x,c2.y,c2.z,c2.w};
        const float nf[12] = {n0.x,n0.y,n0.z,n0.w, n1.x,n1.y,n1.z,n1.w, n2.x,n2.y,n2.z,n2.w};
        const float rf[12] = {r0.x,r0.y,r0.z,r0.w, r1.x,r1.y,r1.z,r1.w, r2.x,r2.y,r2.z,r2.w};
#pragma unroll
        for (int t = 0; t < NBINS; ++t) {
            conf[t] += (double)cf[t];
            cntd[t] += (double)nf[t];
            cord[t] += (double)rf[t];
        }
    }

#pragma unroll
    for (int t = 0; t < NBINS; ++t) {
        for (int o = 32; o > 0; o >>= 1) {
            conf[t] += __shfl_xor(conf[t], o, 64);
            cntd[t] += __shfl_xor(cntd[t], o, 64);
            cord[t] += __shfl_xor(cord[t], o, 64);
        }
    }
    if (lane == 0) {
#pragma unroll
        for (int t = 0; t < NBINS; ++t) {
            s_c[wave][t] = conf[t]; s_n[wave][t] = cntd[t]; s_r[wave][t] = cord[t];
        }
    }
    __syncthreads();

    if (tid == 0) {
        double S[NBINS + 1], G[NBINS + 1], R[NBINS];
        for (int t = 0; t < NBINS; ++t) {
            const double cc = s_c[0][t] + s_c[1][t] + s_c[2][t] + s_c[3][t];
            G[t] = s_n[0][t] + s_n[1][t] + s_n[2][t] + s_n[3][t];
            R[t] = s_r[0][t] + s_r[1][t] + s_r[2][t] + s_r[3][t];
            const double Et = (double)((float)(t * 0.1));   // exact f32 edge
            S[t] = cc + Et * G[t];                           // relu correction
        }
        S[NBINS] = 0.0; G[NBINS] = 0.0;

        double total = 0.0, ece = 0.0;
        for (int j = 0; j < NBINS; ++j) {
            const double c  = G[j] - G[j + 1];     // per-bin count
            const double sc = S[j] - S[j + 1];     // per-bin conf sum
            const double ba = R[j] / c;
            total += c;
            ece   += fabs(sc / c - ba) * c;
            out[1 + j]  = (float)((float)((j + 1) * 0.1) - 0.05f);  // centers
            out[11 + j] = (float)ba;
        }
        out[0] = (float)(ece / total);
    }
}

extern "C" void kernel_launch(void* const* d_in, const int* in_sizes, int n_in,
                              void* d_out, int out_size, void* d_ws, size_t ws_size,
                              hipStream_t stream)
{
    const float* probs  = (const float*)d_in[0];
    const int*   labels = (const int*)  d_in[1];
    float*       out    = (float*)d_out;
    const int n      = in_sizes[1];       // N_SAMPLES
    const int npairs = n / 2;
    const int nf4    = (n * C) / 4;

    float* part = (float*)d_ws;           // fully rewritten each call — no memset

    ece_hist<<<GRIDH, BLOCK, 0, stream>>>((const float4*)probs, part, nf4);
    ece_arg <<<GRIDA, BLOCK, 0, stream>>>((const float4*)probs, (const int2*)labels,
                                          part, npairs);
    ece_reduce<<<1, 256, 0, stream>>>(part, out);
}

// Round 6
// 43.609 us; speedup vs baseline: 2.5821x; 1.3186x over previous
//
#include <hip/hip_runtime.h>

#define NBINS 10
#define C 10

constexpr int BLOCK = 256;
constexpr int GRIDH = 1024;                         // hist-role blocks (= partial rows)
constexpr int GRIDA = 1024;                         // arg-role blocks
constexpr int PSTR  = 32;                           // padded partial-row stride (floats)
constexpr int PAIRS_PER_TILE = BLOCK;               // 256 pairs = 512 samples / tile
constexpr int F4_PER_TILE    = PAIRS_PER_TILE * 5;  // 1280 float4

// d_ws float layout:
//   [0, GRIDH*PSTR)                 conf' partials (relu/cndmask cumulative sums)
//   [GRIDH*PSTR, 2*GRIDH*PSTR)      cnt partials   (G_t counts, f32-exact < 2^24)
//   [2*GRIDH*PSTR, +GRIDA*PSTR)     cor partials
// Every slot read by ece_reduce is rewritten every call — no memset needed.

__global__ __launch_bounds__(BLOCK) void ece_fused(
    const float4* __restrict__ p4,
    const int2*   __restrict__ l2,
    float*        __restrict__ part,
    int npairs, int nf4)
{
    __shared__ float        s_stage[F4_PER_TILE * 4];   // 20 KB: arg staging / hist reduce scratch
    __shared__ unsigned int s_cor[NBINS];

    const int tid  = threadIdx.x;
    const int lane = tid & 63, wave = tid >> 6;

    const float EDGE[NBINS] = {
        (float)(0*0.1), (float)(1*0.1), (float)(2*0.1), (float)(3*0.1), (float)(4*0.1),
        (float)(5*0.1), (float)(6*0.1), (float)(7*0.1), (float)(8*0.1), (float)(9*0.1)};

    if (blockIdx.x < GRIDH) {
        // ================= hist role: pure coalesced stream, no barriers =================
        float        conf[NBINS];
        unsigned int cnt[NBINS];
#pragma unroll
        for (int t = 0; t < NBINS; ++t) { conf[t] = 0.0f; cnt[t] = 0u; }

        for (int fi = blockIdx.x * BLOCK + tid; fi < nf4; fi += GRIDH * BLOCK) {
            const float4 q = p4[fi];
            const float e[4] = {q.x, q.y, q.z, q.w};
#pragma unroll
            for (int j = 0; j < 4; ++j) {
                const float x = e[j];
                conf[0] += x;                                       // x >= 0: unconditional
                cnt[0]  += (unsigned)__popcll(__ballot(x > EDGE[0]));
#pragma unroll
                for (int t = 1; t < NBINS; ++t) {
                    const bool g = x > EDGE[t];
                    cnt[t]  += (unsigned)__popcll(__ballot(g));     // scalar-pipe popc
                    conf[t] += g ? x : 0.0f;                        // shares the compare
                }
            }
        }

        // conf: 64-lane butterfly; cnt: lane 0 already holds full-wave counts (ballot)
#pragma unroll
        for (int t = 0; t < NBINS; ++t)
            for (int o = 32; o > 0; o >>= 1)
                conf[t] += __shfl_xor(conf[t], o, 64);

        float* s_confr = s_stage;          // [4][NBINS] reuse
        float* s_cntr  = s_stage + 4 * NBINS;
        if (lane == 0) {
#pragma unroll
            for (int t = 0; t < NBINS; ++t) {
                s_confr[wave * NBINS + t] = conf[t];
                s_cntr [wave * NBINS + t] = (float)cnt[t];
            }
        }
        __syncthreads();

        if (tid < 12) {   // 12 slots (2 zero pads) so reduce can float4-load
            float fc = 0.0f, fn = 0.0f;
            if (tid < NBINS) {
#pragma unroll
                for (int w = 0; w < 4; ++w) {
                    fc += s_confr[w * NBINS + tid];
                    fn += s_cntr [w * NBINS + tid];
                }
            }
            part[(size_t)blockIdx.x * PSTR + tid]                = fc;
            part[(size_t)GRIDH * PSTR + blockIdx.x * PSTR + tid] = fn;
        }
    } else {
        // ================= arg role: LDS-staged coalesced pair processing =================
        const int bid2 = blockIdx.x - GRIDH;
        if (tid < NBINS) s_cor[tid] = 0u;

        float4* s4 = reinterpret_cast<float4*>(s_stage);
        const int ntiles = (npairs + PAIRS_PER_TILE - 1) / PAIRS_PER_TILE;

        for (int tile = bid2; tile < ntiles; tile += GRIDA) {
            __syncthreads();   // protect s_stage reuse (and s_cor init on first pass)

            const int f4base = tile * F4_PER_TILE;
#pragma unroll
            for (int k = 0; k < 5; ++k) {
                const int fi = f4base + k * BLOCK + tid;
                float4 q = make_float4(0.0f, 0.0f, 0.0f, 0.0f);
                if (fi < nf4) q = p4[fi];
                s4[k * BLOCK + tid] = q;                 // linear LDS write
            }
            __syncthreads();

            const int pr = tile * PAIRS_PER_TILE + tid;
            if (pr < npairs) {
                const float4* row = reinterpret_cast<const float4*>(&s_stage[tid * 20]);
                const float4 q0 = row[0], q1 = row[1], q2 = row[2], q3 = row[3], q4 = row[4];
                const int2 lab = l2[pr];

                const float a[C] = {q0.x,q0.y,q0.z,q0.w, q1.x,q1.y,q1.z,q1.w, q2.x,q2.y};
                const float b[C] = {q2.z,q2.w, q3.x,q3.y,q3.z,q3.w, q4.x,q4.y,q4.z,q4.w};

#pragma unroll
                for (int s = 0; s < 2; ++s) {
                    const float* p = (s == 0) ? a : b;   // fully unrolled -> static
                    const int  lbl = (s == 0) ? lab.x : lab.y;

                    float mx = p[0]; int arg = 0;        // first-occurrence argmax
#pragma unroll
                    for (int j = 1; j < C; ++j)
                        if (p[j] > mx) { mx = p[j]; arg = j; }

                    if (arg == lbl) {
                        // ceilf bin (validated bit-exact vs digitize, rounds 1-5)
                        const int im = min((int)ceilf(mx * 10.0f) - 1, NBINS - 1);
                        if (im >= 0) atomicAdd(&s_cor[im], 1u);   // LDS only, ~10% hit
                    }
                }
            }
        }
        __syncthreads();

        if (tid < 12) {
            const float v = (tid < NBINS) ? (float)s_cor[tid] : 0.0f;
            part[(size_t)2 * GRIDH * PSTR + bid2 * PSTR + tid] = v;
        }
    }
}

__global__ __launch_bounds__(256) void ece_reduce(
    const float* __restrict__ part,
    float* __restrict__ out)
{
    __shared__ double s_c[4][NBINS];
    __shared__ double s_n[4][NBINS];
    __shared__ double s_r[4][NBINS];

    const int tid = threadIdx.x;
    const int lane = tid & 63, wave = tid >> 6;

    double conf[NBINS], cntd[NBINS], cord[NBINS];
#pragma unroll
    for (int t = 0; t < NBINS; ++t) { conf[t] = 0.0; cntd[t] = 0.0; cord[t] = 0.0; }

    for (int b = tid; b < GRIDH; b += 256) {
        const float4* rc = reinterpret_cast<const float4*>(part + (size_t)b * PSTR);
        const float4* rn = reinterpret_cast<const float4*>(part + (size_t)GRIDH * PSTR + b * PSTR);
        const float4* rr = reinterpret_cast<const float4*>(part + (size_t)2 * GRIDH * PSTR + b * PSTR);
        const float4 c0 = rc[0], c1 = rc[1], c2 = rc[2];
        const float4 n0 = rn[0], n1 = rn[1], n2 = rn[2];
        const float4 r0 = rr[0], r1 = rr[1], r2 = rr[2];
        const float cf[12] = {c0.x,c0.y,c0.z,c0.w, c1.x,c1.y,c1.z,c1.w, c2.x,c2.y,c2.z,c2.w};
        const float nf[12] = {n0.x,n0.y,n0.z,n0.w, n1.x,n1.y,n1.z,n1.w, n2.x,n2.y,n2.z,n2.w};
        const float rf[12] = {r0.x,r0.y,r0.z,r0.w, r1.x,r1.y,r1.z,r1.w, r2.x,r2.y,r2.z,r2.w};
#pragma unroll
        for (int t = 0; t < NBINS; ++t) {
            conf[t] += (double)cf[t];
            cntd[t] += (double)nf[t];
            cord[t] += (double)rf[t];
        }
    }

#pragma unroll
    for (int t = 0; t < NBINS; ++t) {
        for (int o = 32; o > 0; o >>= 1) {
            conf[t] += __shfl_xor(conf[t], o, 64);
            cntd[t] += __shfl_xor(cntd[t], o, 64);
            cord[t] += __shfl_xor(cord[t], o, 64);
        }
    }
    if (lane == 0) {
#pragma unroll
        for (int t = 0; t < NBINS; ++t) {
            s_c[wave][t] = conf[t]; s_n[wave][t] = cntd[t]; s_r[wave][t] = cord[t];
        }
    }
    __syncthreads();

    if (tid == 0) {
        double S[NBINS + 1], G[NBINS + 1], R[NBINS];
        for (int t = 0; t < NBINS; ++t) {
            G[t] = s_n[0][t] + s_n[1][t] + s_n[2][t] + s_n[3][t];
            R[t] = s_r[0][t] + s_r[1][t] + s_r[2][t] + s_r[3][t];
            S[t] = s_c[0][t] + s_c[1][t] + s_c[2][t] + s_c[3][t];
        }
        S[NBINS] = 0.0; G[NBINS] = 0.0;

        double total = 0.0, ece = 0.0;
        for (int j = 0; j < NBINS; ++j) {
            const double c  = G[j] - G[j + 1];     // per-bin count
            const double sc = S[j] - S[j + 1];     // per-bin conf sum
            const double ba = R[j] / c;
            total += c;
            ece   += fabs(sc / c - ba) * c;
            out[1 + j]  = (float)((float)((j + 1) * 0.1) - 0.05f);  // centers
            out[11 + j] = (float)ba;
        }
        out[0] = (float)(ece / total);
    }
}

extern "C" void kernel_launch(void* const* d_in, const int* in_sizes, int n_in,
                              void* d_out, int out_size, void* d_ws, size_t ws_size,
                              hipStream_t stream)
{
    const float* probs  = (const float*)d_in[0];
    const int*   labels = (const int*)  d_in[1];
    float*       out    = (float*)d_out;
    const int n      = in_sizes[1];       // N_SAMPLES
    const int npairs = n / 2;
    const int nf4    = (n * C) / 4;

    float* part = (float*)d_ws;           // fully rewritten each call — no memset

    ece_fused<<<GRIDH + GRIDA, BLOCK, 0, stream>>>((const float4*)probs,
                                                   (const int2*)labels,
                                                   part, npairs, nf4);
    ece_reduce<<<1, 256, 0, stream>>>(part, out);
}